// Round 14
// baseline (508.998 us; speedup 1.0000x reference)
//
#include <hip/hip_runtime.h>
#include <stdint.h>

typedef unsigned short u16;
typedef __attribute__((ext_vector_type(8))) short bf16x8;    // 8 bf16 (4 VGPRs) — MFMA A/B frag
typedef __attribute__((ext_vector_type(4))) float f32x4;     // 16x16 MFMA C/D frag
typedef __attribute__((ext_vector_type(16))) float f32x16;   // 32x32 MFMA C/D frag

static __device__ __forceinline__ u16 f2bf(float f) {
  uint32_t u = __float_as_uint(f);
  return (u16)((u + 0x7fffu + ((u >> 16) & 1u)) >> 16);   // RNE
}
static __device__ __forceinline__ float bf2f(u16 h) {
  return __uint_as_float(((uint32_t)h) << 16);
}

static __device__ __forceinline__ void gload_lds16(const void* g, void* l) {
  __builtin_amdgcn_global_load_lds((const __attribute__((address_space(1))) void*)g,
                                   (__attribute__((address_space(3))) void*)l, 16, 0, 0);
}

// ---------------- elementwise f32 -> bf16 cast ----------------
__global__ __launch_bounds__(256) void cast_bf16_kernel(const float* __restrict__ in,
                                                        u16* __restrict__ out, int n4) {
  int idx = blockIdx.x * 256 + threadIdx.x;
  if (idx >= n4) return;
  float4 v = ((const float4*)in)[idx];
  u16 o0 = f2bf(v.x), o1 = f2bf(v.y), o2 = f2bf(v.z), o3 = f2bf(v.w);
  uint2 packed;
  packed.x = (uint32_t)o0 | ((uint32_t)o1 << 16);
  packed.y = (uint32_t)o2 | ((uint32_t)o3 << 16);
  ((uint2*)out)[idx] = packed;
}

// -------- deg prep: f32 [4096][4096] -> bf16 row-major AND bf16 transposed --------
__global__ __launch_bounds__(256) void deg_prep_kernel(const float* __restrict__ in,
                                                       u16* __restrict__ degb,
                                                       u16* __restrict__ degt) {
  __shared__ float t[64][72];
  const int r0 = blockIdx.y * 64, c0 = blockIdx.x * 64;
  const int tid = threadIdx.x;
  const int rr = tid >> 4;          // 0..15
  const int c4 = (tid & 15) * 4;
#pragma unroll
  for (int s = 0; s < 4; ++s) {
    const int row = r0 + rr + s * 16;
    float4 v = *(const float4*)&in[(size_t)row * 4096 + c0 + c4];
    *(float4*)&t[rr + s * 16][c4] = v;
    uint2 p;
    p.x = (uint32_t)f2bf(v.x) | ((uint32_t)f2bf(v.y) << 16);
    p.y = (uint32_t)f2bf(v.z) | ((uint32_t)f2bf(v.w) << 16);
    *(uint2*)&degb[(size_t)row * 4096 + c0 + c4] = p;
  }
  __syncthreads();
  const int oc = tid >> 2;          // 0..63  (output row = input col)
  const int or16 = (tid & 3) * 16;
  bf16x8 o0, o1;
#pragma unroll
  for (int u = 0; u < 8; ++u) o0[u] = (short)f2bf(t[or16 + u][oc]);
#pragma unroll
  for (int u = 0; u < 8; ++u) o1[u] = (short)f2bf(t[or16 + 8 + u][oc]);
  *(bf16x8*)&degt[(size_t)(c0 + oc) * 4096 + r0 + or16] = o0;
  *(bf16x8*)&degt[(size_t)(c0 + oc) * 4096 + r0 + or16 + 8] = o1;
}

// ---------------- transpose: bf16 [4096][4096] -> bf16 transposed ----------------
__global__ __launch_bounds__(256) void transpose_bf16_kernel(const u16* __restrict__ in,
                                                             u16* __restrict__ out) {
  __shared__ u16 t[64][72];
  const int r0 = blockIdx.y * 64, c0 = blockIdx.x * 64;
  const int tid = threadIdx.x;
  const int rr = tid >> 3;
  const int c8 = (tid & 7) * 8;
#pragma unroll
  for (int s = 0; s < 2; ++s) {
    bf16x8 v = *(const bf16x8*)&in[(size_t)(r0 + rr + s * 32) * 4096 + c0 + c8];
    *(bf16x8*)&t[rr + s * 32][c8] = v;
  }
  __syncthreads();
  const int oc = tid >> 2;
  const int or16 = (tid & 3) * 16;
  bf16x8 o0, o1;
#pragma unroll
  for (int u = 0; u < 8; ++u) o0[u] = (short)t[or16 + u][oc];
#pragma unroll
  for (int u = 0; u < 8; ++u) o1[u] = (short)t[or16 + 8 + u][oc];
  *(bf16x8*)&out[(size_t)(c0 + oc) * 4096 + r0 + or16] = o0;
  *(bf16x8*)&out[(size_t)(c0 + oc) * 4096 + r0 + or16 + 8] = o1;
}

// ---------------- combine split-K partials + leaky -> bf16 ----------------
__global__ __launch_bounds__(256) void combine_leaky_kernel(const float* __restrict__ P,
                                                            u16* __restrict__ out, int n4) {
  int idx = blockIdx.x * 256 + threadIdx.x;
  if (idx >= n4) return;
  float4 a = ((const float4*)P)[idx];
  float4 b = ((const float4*)(P + (size_t)4096 * 512))[idx];
  float s0 = a.x + b.x, s1 = a.y + b.y, s2 = a.z + b.z, s3 = a.w + b.w;
  s0 = s0 >= 0.f ? s0 : 0.1f * s0;
  s1 = s1 >= 0.f ? s1 : 0.1f * s1;
  s2 = s2 >= 0.f ? s2 : 0.1f * s2;
  s3 = s3 >= 0.f ? s3 : 0.1f * s3;
  uint2 p;
  p.x = (uint32_t)f2bf(s0) | ((uint32_t)f2bf(s1) << 16);
  p.y = (uint32_t)f2bf(s2) | ((uint32_t)f2bf(s3) << 16);
  ((uint2*)out)[idx] = p;
}

// ------- kern[i][t] = sum_j H[i][j]*W2[t][j], vectorized (float4 W2, uint2 H) -------
__global__ __launch_bounds__(256) void kern_reduce_kernel(const u16* __restrict__ H,
                                                          const float* __restrict__ W2,
                                                          float* __restrict__ kern) {
  const int i = blockIdx.x;
  const int tid = threadIdx.x;
  float acc[9];
#pragma unroll
  for (int t = 0; t < 9; ++t) acc[t] = 0.f;
#pragma unroll
  for (int it = 0; it < 4; ++it) {
    const int j = it * 1024 + tid * 4;
    uint2 hv = *(const uint2*)&H[(size_t)i * 4096 + j];
    float h0 = bf2f((u16)(hv.x & 0xffff)), h1 = bf2f((u16)(hv.x >> 16));
    float h2 = bf2f((u16)(hv.y & 0xffff)), h3 = bf2f((u16)(hv.y >> 16));
#pragma unroll
    for (int t = 0; t < 9; ++t) {
      float4 w = *(const float4*)&W2[t * 4096 + j];
      acc[t] += h0 * w.x + h1 * w.y + h2 * w.z + h3 * w.w;
    }
  }
  __shared__ float red[4 * 9];
  const int lane = tid & 63, wid = tid >> 6;
#pragma unroll
  for (int t = 0; t < 9; ++t) {
    float v = acc[t];
#pragma unroll
    for (int off = 32; off > 0; off >>= 1) v += __shfl_down(v, off);
    if (lane == 0) red[wid * 9 + t] = v;
  }
  __syncthreads();
  if (tid < 9) kern[(size_t)i * 9 + tid] = red[tid] + red[9 + tid] + red[18 + tid] + red[27 + tid];
}

// ---------------- depthwise 3x3 conv + leaky -> bf16 ----------------
__global__ __launch_bounds__(256) void dwconv_kernel(const float* __restrict__ x,
                                                     const float* __restrict__ kern,
                                                     u16* __restrict__ V) {
  const int ch = blockIdx.x;
  __shared__ float img[4096];
  const float* src = x + (size_t)ch * 4096;
#pragma unroll
  for (int s = 0; s < 4; ++s)
    ((float4*)img)[s * 256 + threadIdx.x] = ((const float4*)src)[s * 256 + threadIdx.x];
  float kv[9];
#pragma unroll
  for (int t = 0; t < 9; ++t) kv[t] = kern[(size_t)ch * 9 + t];
  __syncthreads();
#pragma unroll
  for (int s = 0; s < 16; ++s) {
    const int p = s * 256 + threadIdx.x;
    const int h = p >> 6, w = p & 63;
    float sum = 0.f;
#pragma unroll
    for (int dh = -1; dh <= 1; ++dh) {
      const int hh = h + dh;
      if ((unsigned)hh < 64u) {
#pragma unroll
        for (int dw = -1; dw <= 1; ++dw) {
          const int wwi = w + dw;
          if ((unsigned)wwi < 64u) sum += img[hh * 64 + wwi] * kv[(dh + 1) * 3 + (dw + 1)];
        }
      }
    }
    sum = sum >= 0.f ? sum : 0.1f * sum;
    V[(size_t)ch * 4096 + p] = f2bf(sum);
  }
}

// ---------------- NT GEMM (16x16x32 MFMA): C[m][n] = sum_k A[m][k]*B[n][k] ----------------
// EPI: 0 = leaky -> bf16 ; 1 = sigmoid -> bf16 ; 2 = +bias +deg*att -> f32 ;
//      3 = raw f32 partial (split-K over blockIdx.z)
// 2D XCD chunking (r13-verified) + both-sides LDS XOR swizzle (r6-verified).
template <int EPI>
__global__ __launch_bounds__(256, 4) void gemm_nt(const u16* __restrict__ A,
                                                  const u16* __restrict__ B,
                                                  void* __restrict__ Cout,
                                                  int M, int N, int K,
                                                  const float* __restrict__ bias,
                                                  const float* __restrict__ degf,
                                                  const u16* __restrict__ att) {
  __shared__ u16 Asm[128 * 64];
  __shared__ u16 Bsm[128 * 64];
  const int tid = threadIdx.x;
  const int lane = tid & 63;
  const int wid = tid >> 6;
  const int wr = wid >> 1, wc = wid & 1;       // 2x2 wave grid, 64x64 per wave
  const int gx = gridDim.x, gy = gridDim.y;
  const int lin = blockIdx.y * gx + blockIdx.x;
  const int xcd = lin & 7;
  const int idx8 = lin >> 3;
  const int cc = gx >> 2, cr = gy >> 1;
  const int bn = ((xcd & 3) * cc + idx8 / cr) * 128;
  const int bm = ((xcd >> 2) * cr + idx8 % cr) * 128;
  const int kper = K / gridDim.z;
  const int k0 = blockIdx.z * kper, k1 = k0 + kper;

  const int srow = tid >> 3;
  const int sseg = tid & 7;
  const int ssw  = (sseg ^ (srow & 7)) * 8;
  const int l15 = lane & 15;
  const int seg0 = lane >> 4;
  const int lx7 = l15 & 7;

  f32x4 acc[4][4];
#pragma unroll
  for (int m = 0; m < 4; ++m)
#pragma unroll
    for (int n = 0; n < 4; ++n) acc[m][n] = (f32x4){0.f, 0.f, 0.f, 0.f};

  const size_t aBase = (size_t)bm * K;
  const size_t bBase = (size_t)bn * K;

  for (int kt = k0; kt < k1; kt += 64) {
    __syncthreads();
#pragma unroll
    for (int bi = 0; bi < 4; ++bi) {
      const u16* ga = A + aBase + (size_t)(bi * 32 + srow) * K + kt + ssw;
      gload_lds16(ga, &Asm[(bi * 32 + srow) * 64 + sseg * 8]);
      const u16* gb = B + bBase + (size_t)(bi * 32 + srow) * K + kt + ssw;
      gload_lds16(gb, &Bsm[(bi * 32 + srow) * 64 + sseg * 8]);
    }
    __syncthreads();
#pragma unroll
    for (int ks = 0; ks < 2; ++ks) {
      bf16x8 av[4], bv[4];
#pragma unroll
      for (int m = 0; m < 4; ++m)
        av[m] = *(const bf16x8*)&Asm[(wr * 64 + m * 16 + l15) * 64 +
                                     (((ks * 4 + seg0) ^ lx7) * 8)];
#pragma unroll
      for (int n = 0; n < 4; ++n)
        bv[n] = *(const bf16x8*)&Bsm[(wc * 64 + n * 16 + l15) * 64 +
                                     (((ks * 4 + seg0) ^ lx7) * 8)];
#pragma unroll
      for (int m = 0; m < 4; ++m)
#pragma unroll
        for (int n = 0; n < 4; ++n)
          acc[m][n] = __builtin_amdgcn_mfma_f32_16x16x32_bf16(av[m], bv[n], acc[m][n], 0, 0, 0);
    }
  }

#pragma unroll
  for (int m = 0; m < 4; ++m) {
    const int row0 = bm + wr * 64 + m * 16 + (lane >> 4) * 4;
#pragma unroll
    for (int n = 0; n < 4; ++n) {
      const int col = bn + wc * 64 + n * 16 + l15;
#pragma unroll
      for (int j = 0; j < 4; ++j) {
        const int row = row0 + j;
        float v = acc[m][n][j];
        const size_t idx = (size_t)row * N + col;
        if (EPI == 0) {
          v = v >= 0.f ? v : 0.1f * v;
          ((u16*)Cout)[idx] = f2bf(v);
        } else if (EPI == 1) {
          v = 1.f / (1.f + __expf(-v));
          ((u16*)Cout)[idx] = f2bf(v);
        } else if (EPI == 2) {
          v += bias[row] + degf[idx] * bf2f(att[idx]);
          ((float*)Cout)[idx] = v;
        } else {
          ((float*)Cout)[(size_t)blockIdx.z * ((size_t)M * N) + idx] = v;
        }
      }
    }
  }
}

// preserve instantiation set (rule-19 codegen-context insurance)
template __global__ void gemm_nt<0>(const u16*, const u16*, void*, int, int, int,
                                    const float*, const float*, const u16*);

// ======== NT GEMM via v_mfma_f32_32x32x16_bf16 (H-GEMM only): leaky -> bf16 ========
// Same 128x128 tile / staging / swizzle as gemm_nt. Per wave: 2x2 frags of 32x32.
// A/B frag (8 bf16): row(col)=lane&31, k=(lane>>5)*8+j within each K=16 slice.
// C/D frag (16 f32): col=lane&31, row=(reg&3)+8*(reg>>2)+4*(lane>>5)  [m74/m101].
// MFMA cycles per K-step: 16x8=128 vs 32x5=160 for 16x16x32 (-20% matrix-pipe).
__global__ __launch_bounds__(256, 4) void gemm32_nt(const u16* __restrict__ A,
                                                    const u16* __restrict__ B,
                                                    u16* __restrict__ Cout,
                                                    int N, int K) {
  __shared__ u16 Asm[128 * 64];
  __shared__ u16 Bsm[128 * 64];
  const int tid = threadIdx.x;
  const int lane = tid & 63;
  const int wid = tid >> 6;
  const int wr = wid >> 1, wc = wid & 1;       // 2x2 wave grid, 64x64 per wave
  const int gx = gridDim.x, gy = gridDim.y;
  const int lin = blockIdx.y * gx + blockIdx.x;
  const int xcd = lin & 7;
  const int idx8 = lin >> 3;
  const int cc = gx >> 2, cr = gy >> 1;
  const int bn = ((xcd & 3) * cc + idx8 / cr) * 128;
  const int bm = ((xcd >> 2) * cr + idx8 % cr) * 128;

  const int srow = tid >> 3;
  const int sseg = tid & 7;
  const int ssw  = (sseg ^ (srow & 7)) * 8;
  const int l31 = lane & 31;
  const int g2  = lane >> 5;                   // 0..1 : k-halves of each 16-K slice
  const int lx7 = l31 & 7;                     // read-side XOR key (row&7)

  f32x16 acc[2][2];
#pragma unroll
  for (int m = 0; m < 2; ++m)
#pragma unroll
    for (int n = 0; n < 2; ++n)
#pragma unroll
      for (int r = 0; r < 16; ++r) acc[m][n][r] = 0.f;

  const size_t aBase = (size_t)bm * K;
  const size_t bBase = (size_t)bn * K;

  for (int kt = 0; kt < K; kt += 64) {
    __syncthreads();
#pragma unroll
    for (int bi = 0; bi < 4; ++bi) {
      const u16* ga = A + aBase + (size_t)(bi * 32 + srow) * K + kt + ssw;
      gload_lds16(ga, &Asm[(bi * 32 + srow) * 64 + sseg * 8]);
      const u16* gb = B + bBase + (size_t)(bi * 32 + srow) * K + kt + ssw;
      gload_lds16(gb, &Bsm[(bi * 32 + srow) * 64 + sseg * 8]);
    }
    __syncthreads();
#pragma unroll
    for (int ks = 0; ks < 4; ++ks) {           // four K=16 slices per 64-K step
      const int seg = ks * 2 + g2;             // 8-elem segment index 0..7
      bf16x8 av[2], bv[2];
#pragma unroll
      for (int m = 0; m < 2; ++m)
        av[m] = *(const bf16x8*)&Asm[(wr * 64 + m * 32 + l31) * 64 +
                                     ((seg ^ lx7) * 8)];
#pragma unroll
      for (int n = 0; n < 2; ++n)
        bv[n] = *(const bf16x8*)&Bsm[(wc * 64 + n * 32 + l31) * 64 +
                                     ((seg ^ lx7) * 8)];
#pragma unroll
      for (int m = 0; m < 2; ++m)
#pragma unroll
        for (int n = 0; n < 2; ++n)
          acc[m][n] = __builtin_amdgcn_mfma_f32_32x32x16_bf16(av[m], bv[n], acc[m][n], 0, 0, 0);
    }
  }

  // epilogue: leaky -> bf16; row=(reg&3)+8*(reg>>2)+4*(lane>>5), col=lane&31
#pragma unroll
  for (int m = 0; m < 2; ++m) {
#pragma unroll
    for (int n = 0; n < 2; ++n) {
      const int col = bn + wc * 64 + n * 32 + l31;
#pragma unroll
      for (int r = 0; r < 16; ++r) {
        const int row = bm + wr * 64 + m * 32 + (r & 3) + 8 * (r >> 2) + 4 * g2;
        float v = acc[m][n][r];
        v = v >= 0.f ? v : 0.1f * v;
        Cout[(size_t)row * N + col] = f2bf(v);
      }
    }
  }
}

extern "C" void kernel_launch(void* const* d_in, const int* in_sizes, int n_in,
                              void* d_out, int out_size, void* d_ws, size_t ws_size,
                              hipStream_t stream) {
  const float* xc  = (const float*)d_in[0];   // (1,4096,64,64)
  const float* deg = (const float*)d_in[1];   // (4096,4096)
  const float* W1  = (const float*)d_in[2];   // (4096,4096)
  const float* W2  = (const float*)d_in[3];   // (9,4096)
  const float* Wc  = (const float*)d_in[4];   // (4096,4096)
  const float* bc  = (const float*)d_in[5];   // (4096,)
  const float* Wd1 = (const float*)d_in[6];   // (512,4096)
  const float* Wd2 = (const float*)d_in[7];   // (4096,512)
  float* out = (float*)d_out;

  char* ws = (char*)d_ws;
  const size_t MB = 1ull << 20;
  u16* RA    = (u16*)(ws + 0 * MB);     // 32MB: degT -> W1_b -> V
  u16* RB    = (u16*)(ws + 32 * MB);    // 32MB: deg_b -> Vt
  u16* RC    = (u16*)(ws + 64 * MB);    // 32MB: hid partials(f32) -> H -> Wc_b
  u16* RATT  = (u16*)(ws + 96 * MB);    // 32MB: att (bf16)
  u16* WD1B  = (u16*)(ws + 128 * MB);   // 4MB
  u16* WD2B  = (u16*)(ws + 132 * MB);   // 4MB
  u16* HIDT  = (u16*)(ws + 136 * MB);   // 4MB
  float* KERN = (float*)(ws + 140 * MB); // 144KB

  // ---- CA branch ----
  cast_bf16_kernel<<<2048, 256, 0, stream>>>(Wd1, WD1B, 512 * 4096 / 4);
  cast_bf16_kernel<<<2048, 256, 0, stream>>>(Wd2, WD2B, 4096 * 512 / 4);
  deg_prep_kernel<<<dim3(64, 64), 256, 0, stream>>>(deg, RB, RA);   // deg_b(RB), degT(RA)
  // hidT[p][o] = sum_c degT[p][c]*Wd1[o][c] : M=4096 N=512 K=4096, split-K=2 -> f32 partials
  gemm_nt<3><<<dim3(4, 32, 2), 256, 0, stream>>>(RA, WD1B, (float*)RC, 4096, 512, 4096,
                                                 nullptr, nullptr, nullptr);
  combine_leaky_kernel<<<2048, 256, 0, stream>>>((const float*)RC, HIDT, 4096 * 512 / 4);
  // att[o][p] = sigmoid(sum_k Wd2[o][k]*hidT[p][k]) : M=4096 N=4096 K=512
  gemm_nt<1><<<dim3(32, 32), 256, 0, stream>>>(WD2B, HIDT, RATT, 4096, 4096, 512,
                                               nullptr, nullptr, nullptr);

  // ---- dynamic kernel generation ----
  cast_bf16_kernel<<<16384, 256, 0, stream>>>(W1, RA, 4096 * 4096 / 4);   // W1_b (degT dead)
  // H[i][j] = leaky(sum_k deg[i][k]*W1[j][k]) : 4096^3 via 32x32x16 MFMA
  gemm32_nt<<<dim3(32, 32), 256, 0, stream>>>(RB, RA, RC, 4096, 4096);    // H -> RC
  kern_reduce_kernel<<<4096, 256, 0, stream>>>(RC, W2, KERN);

  // ---- depthwise conv + transpose ----
  dwconv_kernel<<<4096, 256, 0, stream>>>(xc, KERN, RA);                  // V -> RA (W1_b dead)
  transpose_bf16_kernel<<<dim3(64, 64), 256, 0, stream>>>(RA, RB);        // Vt -> RB (deg_b dead)

  // ---- 1x1 conv + fused epilogue ----
  cast_bf16_kernel<<<16384, 256, 0, stream>>>(Wc, RC, 4096 * 4096 / 4);   // Wc_b -> RC (H dead)
  // out[o][p] = sum_c Wc[o][c]*Vt[p][c] + bc[o] + deg[o][p]*att[o][p] : 4096^3
  gemm_nt<2><<<dim3(32, 32), 256, 0, stream>>>(RC, RB, out, 4096, 4096, 4096,
                                               bc, deg, RATT);
}

// Round 15
// 497.127 us; speedup vs baseline: 1.0239x; 1.0239x over previous
//
#include <hip/hip_runtime.h>
#include <stdint.h>

typedef unsigned short u16;
typedef __attribute__((ext_vector_type(8))) short bf16x8;    // 8 bf16 (4 VGPRs) — MFMA A/B frag
typedef __attribute__((ext_vector_type(4))) float f32x4;     // 16x16 MFMA C/D frag

static __device__ __forceinline__ u16 f2bf(float f) {
  uint32_t u = __float_as_uint(f);
  return (u16)((u + 0x7fffu + ((u >> 16) & 1u)) >> 16);   // RNE
}
static __device__ __forceinline__ float bf2f(u16 h) {
  return __uint_as_float(((uint32_t)h) << 16);
}

static __device__ __forceinline__ void gload_lds16(const void* g, void* l) {
  __builtin_amdgcn_global_load_lds((const __attribute__((address_space(1))) void*)g,
                                   (__attribute__((address_space(3))) void*)l, 16, 0, 0);
}

// ---------------- elementwise f32 -> bf16 cast ----------------
__global__ __launch_bounds__(256) void cast_bf16_kernel(const float* __restrict__ in,
                                                        u16* __restrict__ out, int n4) {
  int idx = blockIdx.x * 256 + threadIdx.x;
  if (idx >= n4) return;
  float4 v = ((const float4*)in)[idx];
  u16 o0 = f2bf(v.x), o1 = f2bf(v.y), o2 = f2bf(v.z), o3 = f2bf(v.w);
  uint2 packed;
  packed.x = (uint32_t)o0 | ((uint32_t)o1 << 16);
  packed.y = (uint32_t)o2 | ((uint32_t)o3 << 16);
  ((uint2*)out)[idx] = packed;
}

// -------- deg prep: f32 [4096][4096] -> bf16 row-major AND bf16 transposed --------
__global__ __launch_bounds__(256) void deg_prep_kernel(const float* __restrict__ in,
                                                       u16* __restrict__ degb,
                                                       u16* __restrict__ degt) {
  __shared__ float t[64][72];
  const int r0 = blockIdx.y * 64, c0 = blockIdx.x * 64;
  const int tid = threadIdx.x;
  const int rr = tid >> 4;          // 0..15
  const int c4 = (tid & 15) * 4;
#pragma unroll
  for (int s = 0; s < 4; ++s) {
    const int row = r0 + rr + s * 16;
    float4 v = *(const float4*)&in[(size_t)row * 4096 + c0 + c4];
    *(float4*)&t[rr + s * 16][c4] = v;
    uint2 p;
    p.x = (uint32_t)f2bf(v.x) | ((uint32_t)f2bf(v.y) << 16);
    p.y = (uint32_t)f2bf(v.z) | ((uint32_t)f2bf(v.w) << 16);
    *(uint2*)&degb[(size_t)row * 4096 + c0 + c4] = p;
  }
  __syncthreads();
  const int oc = tid >> 2;          // 0..63  (output row = input col)
  const int or16 = (tid & 3) * 16;
  bf16x8 o0, o1;
#pragma unroll
  for (int u = 0; u < 8; ++u) o0[u] = (short)f2bf(t[or16 + u][oc]);
#pragma unroll
  for (int u = 0; u < 8; ++u) o1[u] = (short)f2bf(t[or16 + 8 + u][oc]);
  *(bf16x8*)&degt[(size_t)(c0 + oc) * 4096 + r0 + or16] = o0;
  *(bf16x8*)&degt[(size_t)(c0 + oc) * 4096 + r0 + or16 + 8] = o1;
}

// ---------------- transpose: bf16 (kept compiled; unlaunched this round) ----------------
__global__ __launch_bounds__(256) void transpose_bf16_kernel(const u16* __restrict__ in,
                                                             u16* __restrict__ out) {
  __shared__ u16 t[64][72];
  const int r0 = blockIdx.y * 64, c0 = blockIdx.x * 64;
  const int tid = threadIdx.x;
  const int rr = tid >> 3;
  const int c8 = (tid & 7) * 8;
#pragma unroll
  for (int s = 0; s < 2; ++s) {
    bf16x8 v = *(const bf16x8*)&in[(size_t)(r0 + rr + s * 32) * 4096 + c0 + c8];
    *(bf16x8*)&t[rr + s * 32][c8] = v;
  }
  __syncthreads();
  const int oc = tid >> 2;
  const int or16 = (tid & 3) * 16;
  bf16x8 o0, o1;
#pragma unroll
  for (int u = 0; u < 8; ++u) o0[u] = (short)t[or16 + u][oc];
#pragma unroll
  for (int u = 0; u < 8; ++u) o1[u] = (short)t[or16 + 8 + u][oc];
  *(bf16x8*)&out[(size_t)(c0 + oc) * 4096 + r0 + or16] = o0;
  *(bf16x8*)&out[(size_t)(c0 + oc) * 4096 + r0 + or16 + 8] = o1;
}

// ---------------- combine split-K partials + leaky -> bf16 ----------------
__global__ __launch_bounds__(256) void combine_leaky_kernel(const float* __restrict__ P,
                                                            u16* __restrict__ out, int n4) {
  int idx = blockIdx.x * 256 + threadIdx.x;
  if (idx >= n4) return;
  float4 a = ((const float4*)P)[idx];
  float4 b = ((const float4*)(P + (size_t)4096 * 512))[idx];
  float s0 = a.x + b.x, s1 = a.y + b.y, s2 = a.z + b.z, s3 = a.w + b.w;
  s0 = s0 >= 0.f ? s0 : 0.1f * s0;
  s1 = s1 >= 0.f ? s1 : 0.1f * s1;
  s2 = s2 >= 0.f ? s2 : 0.1f * s2;
  s3 = s3 >= 0.f ? s3 : 0.1f * s3;
  uint2 p;
  p.x = (uint32_t)f2bf(s0) | ((uint32_t)f2bf(s1) << 16);
  p.y = (uint32_t)f2bf(s2) | ((uint32_t)f2bf(s3) << 16);
  ((uint2*)out)[idx] = p;
}

// ------- kern[i][t] = sum_j H[i][j]*W2[t][j], vectorized (float4 W2, uint2 H) -------
__global__ __launch_bounds__(256) void kern_reduce_kernel(const u16* __restrict__ H,
                                                          const float* __restrict__ W2,
                                                          float* __restrict__ kern) {
  const int i = blockIdx.x;
  const int tid = threadIdx.x;
  float acc[9];
#pragma unroll
  for (int t = 0; t < 9; ++t) acc[t] = 0.f;
#pragma unroll
  for (int it = 0; it < 4; ++it) {
    const int j = it * 1024 + tid * 4;
    uint2 hv = *(const uint2*)&H[(size_t)i * 4096 + j];
    float h0 = bf2f((u16)(hv.x & 0xffff)), h1 = bf2f((u16)(hv.x >> 16));
    float h2 = bf2f((u16)(hv.y & 0xffff)), h3 = bf2f((u16)(hv.y >> 16));
#pragma unroll
    for (int t = 0; t < 9; ++t) {
      float4 w = *(const float4*)&W2[t * 4096 + j];
      acc[t] += h0 * w.x + h1 * w.y + h2 * w.z + h3 * w.w;
    }
  }
  __shared__ float red[4 * 9];
  const int lane = tid & 63, wid = tid >> 6;
#pragma unroll
  for (int t = 0; t < 9; ++t) {
    float v = acc[t];
#pragma unroll
    for (int off = 32; off > 0; off >>= 1) v += __shfl_down(v, off);
    if (lane == 0) red[wid * 9 + t] = v;
  }
  __syncthreads();
  if (tid < 9) kern[(size_t)i * 9 + tid] = red[tid] + red[9 + tid] + red[18 + tid] + red[27 + tid];
}

// ------- depthwise 3x3 conv + leaky, TRANSPOSED output: Vt[p][c] (fuses transpose) -------
// Block = (spatial row h) x (64-channel tile). LDS img[dh][c][67] f32: 67-word c-stride
// -> compute-read bank = (3c + w)%32, 2-way residual = free (m136); write side 2-way.
// Store: one bf16x8 per thread per half -> Vt row-contiguous in c (coalesced).
__global__ __launch_bounds__(256) void dwconv_t_kernel(const float* __restrict__ x,
                                                       const float* __restrict__ kern,
                                                       u16* __restrict__ Vt) {
  const int h  = blockIdx.x & 63;
  const int c0 = (blockIdx.x >> 6) * 64;
  __shared__ float img[3][64][67];
  __shared__ float kl[9][68];
  const int tid = threadIdx.x;

  // kern slice: kl[j][c] = kern[(c0+c)*9 + j]
  for (int i = tid; i < 576; i += 256) {
    const int c = i / 9, j = i - c * 9;
    kl[j][c] = kern[(size_t)(c0 + c) * 9 + j];
  }
  // image rows h-1..h+1 for 64 channels; zero-fill at h edges
  {
    const int c = tid >> 2;             // 0..63
    const int ws = (tid & 3) * 16;      // 4 float4 segments
#pragma unroll
    for (int dh = 0; dh < 3; ++dh) {
      const int hh = h + dh - 1;
#pragma unroll
      for (int s = 0; s < 4; ++s) {
        const int w = ws + s * 4;
        float4 v = make_float4(0.f, 0.f, 0.f, 0.f);
        if ((unsigned)hh < 64u)
          v = *(const float4*)&x[(size_t)(c0 + c) * 4096 + hh * 64 + w];
        img[dh][c][w + 0] = v.x; img[dh][c][w + 1] = v.y;
        img[dh][c][w + 2] = v.z; img[dh][c][w + 3] = v.w;
      }
    }
  }
  __syncthreads();

#pragma unroll
  for (int half = 0; half < 2; ++half) {
    const int pw = (tid >> 3) + half * 32;   // w index 0..63
    const int cb = (tid & 7) * 8;            // channel sub-block
    float s[8];
#pragma unroll
    for (int c = 0; c < 8; ++c) s[c] = 0.f;
#pragma unroll
    for (int dh = 0; dh < 3; ++dh) {
#pragma unroll
      for (int dw = 0; dw < 3; ++dw) {
        const int wv = pw + dw - 1;
        if ((unsigned)wv < 64u) {
#pragma unroll
          for (int c = 0; c < 8; ++c)
            s[c] += img[dh][cb + c][wv] * kl[dh * 3 + dw][cb + c];
        }
      }
    }
    bf16x8 o;
#pragma unroll
    for (int c = 0; c < 8; ++c) {
      float v = s[c];
      v = v >= 0.f ? v : 0.1f * v;
      o[c] = (short)f2bf(v);
    }
    *(bf16x8*)&Vt[(size_t)(h * 64 + pw) * 4096 + c0 + cb] = o;
  }
}

// ---------------- NT GEMM (16x16x32 MFMA): C[m][n] = sum_k A[m][k]*B[n][k] ----------------
// EPI: 0 = leaky -> bf16 ; 1 = sigmoid -> bf16 ; 2 = +bias +deg*att -> f32 ;
//      3 = raw f32 partial (split-K over blockIdx.z)
// 2D XCD chunking (r13-verified) + both-sides LDS XOR swizzle (r6-verified).
template <int EPI>
__global__ __launch_bounds__(256, 4) void gemm_nt(const u16* __restrict__ A,
                                                  const u16* __restrict__ B,
                                                  void* __restrict__ Cout,
                                                  int M, int N, int K,
                                                  const float* __restrict__ bias,
                                                  const float* __restrict__ degf,
                                                  const u16* __restrict__ att) {
  __shared__ u16 Asm[128 * 64];
  __shared__ u16 Bsm[128 * 64];
  const int tid = threadIdx.x;
  const int lane = tid & 63;
  const int wid = tid >> 6;
  const int wr = wid >> 1, wc = wid & 1;       // 2x2 wave grid, 64x64 per wave
  const int gx = gridDim.x, gy = gridDim.y;
  const int lin = blockIdx.y * gx + blockIdx.x;
  const int xcd = lin & 7;
  const int idx8 = lin >> 3;
  const int cc = gx >> 2, cr = gy >> 1;
  const int bn = ((xcd & 3) * cc + idx8 / cr) * 128;
  const int bm = ((xcd >> 2) * cr + idx8 % cr) * 128;
  const int kper = K / gridDim.z;
  const int k0 = blockIdx.z * kper, k1 = k0 + kper;

  const int srow = tid >> 3;
  const int sseg = tid & 7;
  const int ssw  = (sseg ^ (srow & 7)) * 8;
  const int l15 = lane & 15;
  const int seg0 = lane >> 4;
  const int lx7 = l15 & 7;

  f32x4 acc[4][4];
#pragma unroll
  for (int m = 0; m < 4; ++m)
#pragma unroll
    for (int n = 0; n < 4; ++n) acc[m][n] = (f32x4){0.f, 0.f, 0.f, 0.f};

  const size_t aBase = (size_t)bm * K;
  const size_t bBase = (size_t)bn * K;

  for (int kt = k0; kt < k1; kt += 64) {
    __syncthreads();
#pragma unroll
    for (int bi = 0; bi < 4; ++bi) {
      const u16* ga = A + aBase + (size_t)(bi * 32 + srow) * K + kt + ssw;
      gload_lds16(ga, &Asm[(bi * 32 + srow) * 64 + sseg * 8]);
      const u16* gb = B + bBase + (size_t)(bi * 32 + srow) * K + kt + ssw;
      gload_lds16(gb, &Bsm[(bi * 32 + srow) * 64 + sseg * 8]);
    }
    __syncthreads();
#pragma unroll
    for (int ks = 0; ks < 2; ++ks) {
      bf16x8 av[4], bv[4];
#pragma unroll
      for (int m = 0; m < 4; ++m)
        av[m] = *(const bf16x8*)&Asm[(wr * 64 + m * 16 + l15) * 64 +
                                     (((ks * 4 + seg0) ^ lx7) * 8)];
#pragma unroll
      for (int n = 0; n < 4; ++n)
        bv[n] = *(const bf16x8*)&Bsm[(wc * 64 + n * 16 + l15) * 64 +
                                     (((ks * 4 + seg0) ^ lx7) * 8)];
#pragma unroll
      for (int m = 0; m < 4; ++m)
#pragma unroll
        for (int n = 0; n < 4; ++n)
          acc[m][n] = __builtin_amdgcn_mfma_f32_16x16x32_bf16(av[m], bv[n], acc[m][n], 0, 0, 0);
    }
  }

#pragma unroll
  for (int m = 0; m < 4; ++m) {
    const int row0 = bm + wr * 64 + m * 16 + (lane >> 4) * 4;
#pragma unroll
    for (int n = 0; n < 4; ++n) {
      const int col = bn + wc * 64 + n * 16 + l15;
#pragma unroll
      for (int j = 0; j < 4; ++j) {
        const int row = row0 + j;
        float v = acc[m][n][j];
        const size_t idx = (size_t)row * N + col;
        if (EPI == 0) {
          v = v >= 0.f ? v : 0.1f * v;
          ((u16*)Cout)[idx] = f2bf(v);
        } else if (EPI == 1) {
          v = 1.f / (1.f + __expf(-v));
          ((u16*)Cout)[idx] = f2bf(v);
        } else if (EPI == 2) {
          v += bias[row] + degf[idx] * bf2f(att[idx]);
          ((float*)Cout)[idx] = v;
        } else {
          ((float*)Cout)[(size_t)blockIdx.z * ((size_t)M * N) + idx] = v;
        }
      }
    }
  }
}

// preserve instantiation set (rule-19 codegen-context insurance)
template __global__ void gemm_nt<0>(const u16*, const u16*, void*, int, int, int,
                                    const float*, const float*, const u16*);

extern "C" void kernel_launch(void* const* d_in, const int* in_sizes, int n_in,
                              void* d_out, int out_size, void* d_ws, size_t ws_size,
                              hipStream_t stream) {
  const float* xc  = (const float*)d_in[0];   // (1,4096,64,64)
  const float* deg = (const float*)d_in[1];   // (4096,4096)
  const float* W1  = (const float*)d_in[2];   // (4096,4096)
  const float* W2  = (const float*)d_in[3];   // (9,4096)
  const float* Wc  = (const float*)d_in[4];   // (4096,4096)
  const float* bc  = (const float*)d_in[5];   // (4096,)
  const float* Wd1 = (const float*)d_in[6];   // (512,4096)
  const float* Wd2 = (const float*)d_in[7];   // (4096,512)
  float* out = (float*)d_out;

  char* ws = (char*)d_ws;
  const size_t MB = 1ull << 20;
  u16* RA    = (u16*)(ws + 0 * MB);     // 32MB: degT -> W1_b
  u16* RB    = (u16*)(ws + 32 * MB);    // 32MB: deg_b -> Vt
  u16* RC    = (u16*)(ws + 64 * MB);    // 32MB: hid partials(f32) -> H -> Wc_b
  u16* RATT  = (u16*)(ws + 96 * MB);    // 32MB: att (bf16)
  u16* WD1B  = (u16*)(ws + 128 * MB);   // 4MB
  u16* WD2B  = (u16*)(ws + 132 * MB);   // 4MB
  u16* HIDT  = (u16*)(ws + 136 * MB);   // 4MB
  float* KERN = (float*)(ws + 140 * MB); // 144KB

  // ---- CA branch ----
  cast_bf16_kernel<<<2048, 256, 0, stream>>>(Wd1, WD1B, 512 * 4096 / 4);
  cast_bf16_kernel<<<2048, 256, 0, stream>>>(Wd2, WD2B, 4096 * 512 / 4);
  deg_prep_kernel<<<dim3(64, 64), 256, 0, stream>>>(deg, RB, RA);   // deg_b(RB), degT(RA)
  // hidT[p][o] = sum_c degT[p][c]*Wd1[o][c] : M=4096 N=512 K=4096, split-K=2 -> f32 partials
  gemm_nt<3><<<dim3(4, 32, 2), 256, 0, stream>>>(RA, WD1B, (float*)RC, 4096, 512, 4096,
                                                 nullptr, nullptr, nullptr);
  combine_leaky_kernel<<<2048, 256, 0, stream>>>((const float*)RC, HIDT, 4096 * 512 / 4);
  // att[o][p] = sigmoid(sum_k Wd2[o][k]*hidT[p][k]) : M=4096 N=4096 K=512
  gemm_nt<1><<<dim3(32, 32), 256, 0, stream>>>(WD2B, HIDT, RATT, 4096, 4096, 512,
                                               nullptr, nullptr, nullptr);

  // ---- dynamic kernel generation ----
  cast_bf16_kernel<<<16384, 256, 0, stream>>>(W1, RA, 4096 * 4096 / 4);   // W1_b (degT dead)
  // H[i][j] = leaky(sum_k deg[i][k]*W1[j][k]) : 4096^3
  gemm_nt<0><<<dim3(32, 32), 256, 0, stream>>>(RB, RA, RC, 4096, 4096, 4096,
                                               nullptr, nullptr, nullptr);
  kern_reduce_kernel<<<4096, 256, 0, stream>>>(RC, W2, KERN);

  // ---- depthwise conv with fused transpose: Vt directly ----
  dwconv_t_kernel<<<4096, 256, 0, stream>>>(xc, KERN, RB);                // Vt -> RB (deg_b dead)

  // ---- 1x1 conv + fused epilogue ----
  cast_bf16_kernel<<<16384, 256, 0, stream>>>(Wc, RC, 4096 * 4096 / 4);   // Wc_b -> RC (H dead)
  // out[o][p] = sum_c Wc[o][c]*Vt[p][c] + bc[o] + deg[o][p]*att[o][p] : 4096^3
  gemm_nt<2><<<dim3(32, 32), 256, 0, stream>>>(RC, RB, out, 4096, 4096, 4096,
                                               bc, deg, RATT);
}

// Round 16
// 484.367 us; speedup vs baseline: 1.0509x; 1.0263x over previous
//
#include <hip/hip_runtime.h>
#include <stdint.h>

typedef unsigned short u16;
typedef __attribute__((ext_vector_type(8))) short bf16x8;   // 8 bf16 (4 VGPRs) — MFMA A/B frag
typedef __attribute__((ext_vector_type(4))) float f32x4;    // MFMA C/D frag

static __device__ __forceinline__ u16 f2bf(float f) {
  uint32_t u = __float_as_uint(f);
  return (u16)((u + 0x7fffu + ((u >> 16) & 1u)) >> 16);   // RNE
}
static __device__ __forceinline__ float bf2f(u16 h) {
  return __uint_as_float(((uint32_t)h) << 16);
}

static __device__ __forceinline__ void gload_lds16(const void* g, void* l) {
  __builtin_amdgcn_global_load_lds((const __attribute__((address_space(1))) void*)g,
                                   (__attribute__((address_space(3))) void*)l, 16, 0, 0);
}

// ---------------- elementwise f32 -> bf16 cast ----------------
__global__ __launch_bounds__(256) void cast_bf16_kernel(const float* __restrict__ in,
                                                        u16* __restrict__ out, int n4) {
  int idx = blockIdx.x * 256 + threadIdx.x;
  if (idx >= n4) return;
  float4 v = ((const float4*)in)[idx];
  u16 o0 = f2bf(v.x), o1 = f2bf(v.y), o2 = f2bf(v.z), o3 = f2bf(v.w);
  uint2 packed;
  packed.x = (uint32_t)o0 | ((uint32_t)o1 << 16);
  packed.y = (uint32_t)o2 | ((uint32_t)o3 << 16);
  ((uint2*)out)[idx] = packed;
}

// -------- deg prep: f32 [4096][4096] -> bf16 row-major AND bf16 transposed --------
__global__ __launch_bounds__(256) void deg_prep_kernel(const float* __restrict__ in,
                                                       u16* __restrict__ degb,
                                                       u16* __restrict__ degt) {
  __shared__ float t[64][72];
  const int r0 = blockIdx.y * 64, c0 = blockIdx.x * 64;
  const int tid = threadIdx.x;
  const int rr = tid >> 4;          // 0..15
  const int c4 = (tid & 15) * 4;
#pragma unroll
  for (int s = 0; s < 4; ++s) {
    const int row = r0 + rr + s * 16;
    float4 v = *(const float4*)&in[(size_t)row * 4096 + c0 + c4];
    *(float4*)&t[rr + s * 16][c4] = v;
    uint2 p;
    p.x = (uint32_t)f2bf(v.x) | ((uint32_t)f2bf(v.y) << 16);
    p.y = (uint32_t)f2bf(v.z) | ((uint32_t)f2bf(v.w) << 16);
    *(uint2*)&degb[(size_t)row * 4096 + c0 + c4] = p;
  }
  __syncthreads();
  const int oc = tid >> 2;          // 0..63  (output row = input col)
  const int or16 = (tid & 3) * 16;
  bf16x8 o0, o1;
#pragma unroll
  for (int u = 0; u < 8; ++u) o0[u] = (short)f2bf(t[or16 + u][oc]);
#pragma unroll
  for (int u = 0; u < 8; ++u) o1[u] = (short)f2bf(t[or16 + 8 + u][oc]);
  *(bf16x8*)&degt[(size_t)(c0 + oc) * 4096 + r0 + or16] = o0;
  *(bf16x8*)&degt[(size_t)(c0 + oc) * 4096 + r0 + or16 + 8] = o1;
}

// ---------------- transpose: bf16 [4096][4096] -> bf16 transposed ----------------
__global__ __launch_bounds__(256) void transpose_bf16_kernel(const u16* __restrict__ in,
                                                             u16* __restrict__ out) {
  __shared__ u16 t[64][72];
  const int r0 = blockIdx.y * 64, c0 = blockIdx.x * 64;
  const int tid = threadIdx.x;
  const int rr = tid >> 3;
  const int c8 = (tid & 7) * 8;
#pragma unroll
  for (int s = 0; s < 2; ++s) {
    bf16x8 v = *(const bf16x8*)&in[(size_t)(r0 + rr + s * 32) * 4096 + c0 + c8];
    *(bf16x8*)&t[rr + s * 32][c8] = v;
  }
  __syncthreads();
  const int oc = tid >> 2;
  const int or16 = (tid & 3) * 16;
  bf16x8 o0, o1;
#pragma unroll
  for (int u = 0; u < 8; ++u) o0[u] = (short)t[or16 + u][oc];
#pragma unroll
  for (int u = 0; u < 8; ++u) o1[u] = (short)t[or16 + 8 + u][oc];
  *(bf16x8*)&out[(size_t)(c0 + oc) * 4096 + r0 + or16] = o0;
  *(bf16x8*)&out[(size_t)(c0 + oc) * 4096 + r0 + or16 + 8] = o1;
}

// ---------------- combine split-K partials + leaky -> bf16 ----------------
__global__ __launch_bounds__(256) void combine_leaky_kernel(const float* __restrict__ P,
                                                            u16* __restrict__ out, int n4) {
  int idx = blockIdx.x * 256 + threadIdx.x;
  if (idx >= n4) return;
  float4 a = ((const float4*)P)[idx];
  float4 b = ((const float4*)(P + (size_t)4096 * 512))[idx];
  float s0 = a.x + b.x, s1 = a.y + b.y, s2 = a.z + b.z, s3 = a.w + b.w;
  s0 = s0 >= 0.f ? s0 : 0.1f * s0;
  s1 = s1 >= 0.f ? s1 : 0.1f * s1;
  s2 = s2 >= 0.f ? s2 : 0.1f * s2;
  s3 = s3 >= 0.f ? s3 : 0.1f * s3;
  uint2 p;
  p.x = (uint32_t)f2bf(s0) | ((uint32_t)f2bf(s1) << 16);
  p.y = (uint32_t)f2bf(s2) | ((uint32_t)f2bf(s3) << 16);
  ((uint2*)out)[idx] = p;
}

// ------- kern[i][t] = sum_j H[i][j]*W2[t][j], vectorized (float4 W2, uint2 H) -------
__global__ __launch_bounds__(256) void kern_reduce_kernel(const u16* __restrict__ H,
                                                          const float* __restrict__ W2,
                                                          float* __restrict__ kern) {
  const int i = blockIdx.x;
  const int tid = threadIdx.x;
  float acc[9];
#pragma unroll
  for (int t = 0; t < 9; ++t) acc[t] = 0.f;
#pragma unroll
  for (int it = 0; it < 4; ++it) {
    const int j = it * 1024 + tid * 4;
    uint2 hv = *(const uint2*)&H[(size_t)i * 4096 + j];
    float h0 = bf2f((u16)(hv.x & 0xffff)), h1 = bf2f((u16)(hv.x >> 16));
    float h2 = bf2f((u16)(hv.y & 0xffff)), h3 = bf2f((u16)(hv.y >> 16));
#pragma unroll
    for (int t = 0; t < 9; ++t) {
      float4 w = *(const float4*)&W2[t * 4096 + j];
      acc[t] += h0 * w.x + h1 * w.y + h2 * w.z + h3 * w.w;
    }
  }
  __shared__ float red[4 * 9];
  const int lane = tid & 63, wid = tid >> 6;
#pragma unroll
  for (int t = 0; t < 9; ++t) {
    float v = acc[t];
#pragma unroll
    for (int off = 32; off > 0; off >>= 1) v += __shfl_down(v, off);
    if (lane == 0) red[wid * 9 + t] = v;
  }
  __syncthreads();
  if (tid < 9) kern[(size_t)i * 9 + tid] = red[tid] + red[9 + tid] + red[18 + tid] + red[27 + tid];
}

// ---------------- depthwise 3x3 conv + leaky -> bf16 ----------------
__global__ __launch_bounds__(256) void dwconv_kernel(const float* __restrict__ x,
                                                     const float* __restrict__ kern,
                                                     u16* __restrict__ V) {
  const int ch = blockIdx.x;
  __shared__ float img[4096];
  const float* src = x + (size_t)ch * 4096;
#pragma unroll
  for (int s = 0; s < 4; ++s)
    ((float4*)img)[s * 256 + threadIdx.x] = ((const float4*)src)[s * 256 + threadIdx.x];
  float kv[9];
#pragma unroll
  for (int t = 0; t < 9; ++t) kv[t] = kern[(size_t)ch * 9 + t];
  __syncthreads();
#pragma unroll
  for (int s = 0; s < 16; ++s) {
    const int p = s * 256 + threadIdx.x;
    const int h = p >> 6, w = p & 63;
    float sum = 0.f;
#pragma unroll
    for (int dh = -1; dh <= 1; ++dh) {
      const int hh = h + dh;
      if ((unsigned)hh < 64u) {
#pragma unroll
        for (int dw = -1; dw <= 1; ++dw) {
          const int wwi = w + dw;
          if ((unsigned)wwi < 64u) sum += img[hh * 64 + wwi] * kv[(dh + 1) * 3 + (dw + 1)];
        }
      }
    }
    sum = sum >= 0.f ? sum : 0.1f * sum;
    V[(size_t)ch * 4096 + p] = f2bf(sum);
  }
}

// ---------------- NT GEMM: C[m][n] = sum_k A[m][k]*B[n][k], bf16 in, fp32 acc ----------------
// EPI: 0 = leaky -> bf16 ; 1 = sigmoid -> bf16 ; 2 = +bias +deg*att -> f32 ;
//      3 = raw f32 partial (split-K over blockIdx.z)
// Grid: dim3(gx, gy, kslices); requires gx % 4 == 0 OR gx == 4, and gy % 2 == 0.
// 2D XCD chunking: XCDs form a 2x4 chunk grid; XCD k owns a (gy/2)x(gx/4)-block chunk,
// walked column-major (consecutive blocks share one B panel -> L2-resident; chunk
// working set ~24MB -> global 64MB unique operands L3-resident). Replaces the round-6
// horizontal-stripe swizzle whose per-XCD working set was the whole B (6x HBM re-stream).
// LDS XOR swizzle (rule 21, both-sides): dest linear, source col pre-swizzled seg^(row&7),
// fragment reads apply the same XOR. Residual 2-way aliasing = free (m136).
template <int EPI>
__global__ __launch_bounds__(256, 4) void gemm_nt(const u16* __restrict__ A,
                                                  const u16* __restrict__ B,
                                                  void* __restrict__ Cout,
                                                  int M, int N, int K,
                                                  const float* __restrict__ bias,
                                                  const float* __restrict__ degf,
                                                  const u16* __restrict__ att) {
  __shared__ u16 Asm[128 * 64];
  __shared__ u16 Bsm[128 * 64];
  const int tid = threadIdx.x;
  const int lane = tid & 63;
  const int wid = tid >> 6;
  const int wr = wid >> 1, wc = wid & 1;       // 2x2 wave grid, 64x64 per wave
  // 2D XCD chunk swizzle (bijective; see header comment)
  const int gx = gridDim.x, gy = gridDim.y;
  const int lin = blockIdx.y * gx + blockIdx.x;
  const int xcd = lin & 7;
  const int idx8 = lin >> 3;
  const int cc = gx >> 2, cr = gy >> 1;        // chunk dims in blocks (cols, rows)
  const int bn = ((xcd & 3) * cc + idx8 / cr) * 128;
  const int bm = ((xcd >> 2) * cr + idx8 % cr) * 128;
  // split-K slice
  const int kper = K / gridDim.z;
  const int k0 = blockIdx.z * kper, k1 = k0 + kper;

  const int srow = tid >> 3;                    // 0..31 staging row
  const int sseg = tid & 7;                     // 16B segment idx within 64-elem row
  const int ssw  = (sseg ^ (srow & 7)) * 8;     // swizzled SOURCE elem offset
  const int l15 = lane & 15;
  const int seg0 = lane >> 4;                   // 0..3 base segment of this lane quad
  const int lx7 = l15 & 7;                      // read-side XOR key (row&7)

  f32x4 acc[4][4];
#pragma unroll
  for (int m = 0; m < 4; ++m)
#pragma unroll
    for (int n = 0; n < 4; ++n) acc[m][n] = (f32x4){0.f, 0.f, 0.f, 0.f};

  const size_t aBase = (size_t)bm * K;
  const size_t bBase = (size_t)bn * K;

  for (int kt = k0; kt < k1; kt += 64) {
    __syncthreads();
#pragma unroll
    for (int bi = 0; bi < 4; ++bi) {
      const u16* ga = A + aBase + (size_t)(bi * 32 + srow) * K + kt + ssw;
      gload_lds16(ga, &Asm[(bi * 32 + srow) * 64 + sseg * 8]);
      const u16* gb = B + bBase + (size_t)(bi * 32 + srow) * K + kt + ssw;
      gload_lds16(gb, &Bsm[(bi * 32 + srow) * 64 + sseg * 8]);
    }
    __syncthreads();
#pragma unroll
    for (int ks = 0; ks < 2; ++ks) {
      bf16x8 av[4], bv[4];
#pragma unroll
      for (int m = 0; m < 4; ++m)
        av[m] = *(const bf16x8*)&Asm[(wr * 64 + m * 16 + l15) * 64 +
                                     (((ks * 4 + seg0) ^ lx7) * 8)];
#pragma unroll
      for (int n = 0; n < 4; ++n)
        bv[n] = *(const bf16x8*)&Bsm[(wc * 64 + n * 16 + l15) * 64 +
                                     (((ks * 4 + seg0) ^ lx7) * 8)];
#pragma unroll
      for (int m = 0; m < 4; ++m)
#pragma unroll
        for (int n = 0; n < 4; ++n)
          acc[m][n] = __builtin_amdgcn_mfma_f32_16x16x32_bf16(av[m], bv[n], acc[m][n], 0, 0, 0);
    }
  }

  // epilogue: C/D layout col=lane&15, row=(lane>>4)*4+reg  [m89-verified]
#pragma unroll
  for (int m = 0; m < 4; ++m) {
    const int row0 = bm + wr * 64 + m * 16 + (lane >> 4) * 4;
#pragma unroll
    for (int n = 0; n < 4; ++n) {
      const int col = bn + wc * 64 + n * 16 + l15;
#pragma unroll
      for (int j = 0; j < 4; ++j) {
        const int row = row0 + j;
        float v = acc[m][n][j];
        const size_t idx = (size_t)row * N + col;
        if (EPI == 0) {
          v = v >= 0.f ? v : 0.1f * v;
          ((u16*)Cout)[idx] = f2bf(v);
        } else if (EPI == 1) {
          v = 1.f / (1.f + __expf(-v));
          ((u16*)Cout)[idx] = f2bf(v);
        } else if (EPI == 2) {
          v += bias[row] + degf[idx] * bf2f(att[idx]);
          ((float*)Cout)[idx] = v;
        } else {
          ((float*)Cout)[(size_t)blockIdx.z * ((size_t)M * N) + idx] = v;
        }
      }
    }
  }
}

extern "C" void kernel_launch(void* const* d_in, const int* in_sizes, int n_in,
                              void* d_out, int out_size, void* d_ws, size_t ws_size,
                              hipStream_t stream) {
  const float* xc  = (const float*)d_in[0];   // (1,4096,64,64)
  const float* deg = (const float*)d_in[1];   // (4096,4096)
  const float* W1  = (const float*)d_in[2];   // (4096,4096)
  const float* W2  = (const float*)d_in[3];   // (9,4096)
  const float* Wc  = (const float*)d_in[4];   // (4096,4096)
  const float* bc  = (const float*)d_in[5];   // (4096,)
  const float* Wd1 = (const float*)d_in[6];   // (512,4096)
  const float* Wd2 = (const float*)d_in[7];   // (4096,512)
  float* out = (float*)d_out;

  char* ws = (char*)d_ws;
  const size_t MB = 1ull << 20;
  u16* RA    = (u16*)(ws + 0 * MB);     // 32MB: degT -> W1_b -> V
  u16* RB    = (u16*)(ws + 32 * MB);    // 32MB: deg_b -> Vt
  u16* RC    = (u16*)(ws + 64 * MB);    // 32MB: hid partials(f32) -> H -> Wc_b
  u16* RATT  = (u16*)(ws + 96 * MB);    // 32MB: att (bf16)
  u16* WD1B  = (u16*)(ws + 128 * MB);   // 4MB
  u16* WD2B  = (u16*)(ws + 132 * MB);   // 4MB
  u16* HIDT  = (u16*)(ws + 136 * MB);   // 4MB
  float* KERN = (float*)(ws + 140 * MB); // 144KB

  // ---- CA branch ----
  cast_bf16_kernel<<<2048, 256, 0, stream>>>(Wd1, WD1B, 512 * 4096 / 4);
  cast_bf16_kernel<<<2048, 256, 0, stream>>>(Wd2, WD2B, 4096 * 512 / 4);
  deg_prep_kernel<<<dim3(64, 64), 256, 0, stream>>>(deg, RB, RA);   // deg_b(RB), degT(RA)
  // hidT[p][o] = sum_c degT[p][c]*Wd1[o][c] : M=4096 N=512 K=4096, split-K=2 -> f32 partials
  gemm_nt<3><<<dim3(4, 32, 2), 256, 0, stream>>>(RA, WD1B, (float*)RC, 4096, 512, 4096,
                                                 nullptr, nullptr, nullptr);
  combine_leaky_kernel<<<2048, 256, 0, stream>>>((const float*)RC, HIDT, 4096 * 512 / 4);
  // att[o][p] = sigmoid(sum_k Wd2[o][k]*hidT[p][k]) : M=4096 N=4096 K=512
  gemm_nt<1><<<dim3(32, 32), 256, 0, stream>>>(WD2B, HIDT, RATT, 4096, 4096, 512,
                                               nullptr, nullptr, nullptr);

  // ---- dynamic kernel generation ----
  cast_bf16_kernel<<<16384, 256, 0, stream>>>(W1, RA, 4096 * 4096 / 4);   // W1_b (degT dead)
  // H[i][j] = leaky(sum_k deg[i][k]*W1[j][k]) : 4096^3
  gemm_nt<0><<<dim3(32, 32), 256, 0, stream>>>(RB, RA, RC, 4096, 4096, 4096,
                                               nullptr, nullptr, nullptr);
  kern_reduce_kernel<<<4096, 256, 0, stream>>>(RC, W2, KERN);

  // ---- depthwise conv + transpose ----
  dwconv_kernel<<<4096, 256, 0, stream>>>(xc, KERN, RA);                  // V -> RA (W1_b dead)
  transpose_bf16_kernel<<<dim3(64, 64), 256, 0, stream>>>(RA, RB);        // Vt -> RB (deg_b dead)

  // ---- 1x1 conv + fused epilogue ----
  cast_bf16_kernel<<<16384, 256, 0, stream>>>(Wc, RC, 4096 * 4096 / 4);   // Wc_b -> RC (H dead)
  // out[o][p] = sum_c Wc[o][c]*Vt[p][c] + bc[o] + deg[o][p]*att[o][p] : 4096^3
  gemm_nt<2><<<dim3(32, 32), 256, 0, stream>>>(RC, RB, out, 4096, 4096, 4096,
                                               bc, deg, RATT);
}